// Round 1
// baseline (126.211 us; speedup 1.0000x reference)
//
#include <hip/hip_runtime.h>

// NNSubmulti additive-attention block, MI355X.
// B=16, TK=TQ=128, E=256, H=100.
// Kernel 1 (prep_ac): a[b,i,h] = b1[h] + keys[b,i,:]·W1[h,:E]
//                     c[b,j,h] =         queries[b,j,:]·W1[h,E:]
//                     (H padded to HP=112 with zeros; w2 pad kills the tail)
// Kernel 2 (attn_fused): per block = one batch b × 8 key-rows i:
//   sim[i,j] = sum_h tanh(a[i,h]+c[j,h]) * W2[h]  → softmax_j → ·queries
//   → feature_mul/feature_sub → relu(feat·Wlast^T + blast)

namespace {
constexpr int B  = 16;
constexpr int TQ = 128;
constexpr int TK = 128;
constexpr int E  = 256;
constexpr int H  = 100;
constexpr int HP = 112;   // padded H: 4 quarters x 7 float4
constexpr int G  = 8;     // i-rows per block in attn kernel
}

__device__ __forceinline__ float tanh_fast(float x) {
  // tanh(x) = 1 - 2/(e^{2x}+1); robust: x->+inf => 1, x->-inf => -1
  float e2 = __expf(2.0f * x);
  return 1.0f - 2.0f * __builtin_amdgcn_rcpf(e2 + 1.0f);
}

__global__ __launch_bounds__(256) void prep_ac(
    const float* __restrict__ queries, const float* __restrict__ keys,
    const float* __restrict__ W1, const float* __restrict__ b1,
    float* __restrict__ A, float* __restrict__ C) {
  constexpr int RPB = 16;               // rows per block
  __shared__ float xs[RPB * E];         // 16 KB input tile
  const int t  = threadIdx.x;
  const int r0 = blockIdx.x * RPB;      // grid = 4096/16 = 256 blocks
  const bool isA = (r0 < B * TK);
  const float* src = isA ? (keys + (size_t)r0 * E)
                         : (queries + (size_t)(r0 - B * TK) * E);
  float* dst = isA ? (A + (size_t)r0 * HP)
                   : (C + (size_t)(r0 - B * TK) * HP);
  {
    const float4* s4 = (const float4*)src;
    float4* x4 = (float4*)xs;
    #pragma unroll
    for (int m = 0; m < RPB * E / 4 / 256; ++m)   // 4 iters
      x4[t + m * 256] = s4[t + m * 256];
  }
  __syncthreads();
  const int h  = t & 127;
  const int rg = t >> 7;                // 0/1 -> rows rg*8 .. rg*8+7
  if (h < H) {
    float acc[8];
    const float binit = isA ? b1[h] : 0.0f;
    #pragma unroll
    for (int i = 0; i < 8; ++i) acc[i] = binit;
    const float4* w4 = (const float4*)(W1 + (size_t)h * (2 * E) + (isA ? 0 : E));
    const float4* x4 = (const float4*)xs + (size_t)rg * 8 * (E / 4);
    #pragma unroll 8
    for (int e4 = 0; e4 < E / 4; ++e4) {
      float4 w = w4[e4];                // thread-private W1 row (L2-hot)
      #pragma unroll
      for (int i = 0; i < 8; ++i) {
        float4 xv = x4[i * (E / 4) + e4];   // lane-uniform LDS broadcast
        acc[i] += w.x * xv.x + w.y * xv.y + w.z * xv.z + w.w * xv.w;
      }
    }
    #pragma unroll
    for (int i = 0; i < 8; ++i) dst[(size_t)(rg * 8 + i) * HP + h] = acc[i];
  } else if (h < HP) {
    #pragma unroll
    for (int i = 0; i < 8; ++i) dst[(size_t)(rg * 8 + i) * HP + h] = 0.0f;
  }
}

__global__ __launch_bounds__(512) void attn_fused(
    const float* __restrict__ queries, const float* __restrict__ keys,
    const float* __restrict__ qmask, const float* __restrict__ kmask,
    const float* __restrict__ W2, const float* __restrict__ Wlast,
    const float* __restrict__ blast, const float* __restrict__ A,
    const float* __restrict__ C, float* __restrict__ out) {
  __shared__ float ct[TQ * HP];      // 57.3 KB; dead after phase 1 -> reused as accL
  __shared__ float a_s[G * HP];
  __shared__ float w2s[HP];
  __shared__ float qm[TQ];
  __shared__ float simT[512];
  __shared__ float pL[G * TQ];
  __shared__ float featL[G * 2 * E]; // 16 KB
  __shared__ float red[2];

  const int t   = threadIdx.x;
  const int blk = blockIdx.x;        // 256 blocks
  const int b   = blk >> 4;          // TK/G = 16 blocks per batch
  const int i0  = (blk & 15) * G;

  // ---- stage c[b] (128xHP), a rows, w2, qmask ----
  {
    const float4* s4 = (const float4*)(C + (size_t)b * TQ * HP);
    float4* d4 = (float4*)ct;
    #pragma unroll
    for (int m = 0; m < 7; ++m) d4[t + m * 512] = s4[t + m * 512];  // 3584 f4
  }
  if (t < G * HP / 4)
    ((float4*)a_s)[t] = ((const float4*)(A + ((size_t)b * TK + i0) * HP))[t];
  if (t < HP) w2s[t] = (t < H) ? W2[t] : 0.0f;
  if (t < TQ) qm[t]  = qmask[b * TQ + t];
  __syncthreads();

  // ---- phase 1: sim rows + softmax, one g at a time ----
  const int j = t & (TQ - 1);
  const int q = t >> 7;              // quarter 0..3 of h-range
  float4 cr[7], wr[7];
  {
    const float4* c4 = (const float4*)ct;
    const float4* w4 = (const float4*)w2s;
    #pragma unroll
    for (int k = 0; k < 7; ++k) {
      cr[k] = c4[j * (HP / 4) + q * 7 + k];   // c-column chunk -> registers
      wr[k] = w4[q * 7 + k];
    }
  }
  const float4* a4p = (const float4*)a_s;
  for (int g = 0; g < G; ++g) {
    float acc = 0.0f;
    #pragma unroll
    for (int k = 0; k < 7; ++k) {
      float4 a4 = a4p[g * (HP / 4) + q * 7 + k];  // broadcast read
      float4 cx = cr[k], wv = wr[k];
      acc += tanh_fast(a4.x + cx.x) * wv.x;
      acc += tanh_fast(a4.y + cx.y) * wv.y;
      acc += tanh_fast(a4.z + cx.z) * wv.z;
      acc += tanh_fast(a4.w + cx.w) * wv.w;
    }
    simT[t] = acc;
    __syncthreads();
    float p = 0.0f;
    if (t < TQ) {
      float sv = simT[t] + simT[t + 128] + simT[t + 256] + simT[t + 384];
      if (qm[t] == 0.0f) sv = -4294967295.0f;   // -2^32+1
      p = __expf(sv);                            // |sim|<=24.4: no overflow
      float s = p;
      #pragma unroll
      for (int off = 1; off < 64; off <<= 1) s += __shfl_xor(s, off, 64);
      if ((t & 63) == 0) red[t >> 6] = s;
    }
    __syncthreads();
    if (t < TQ) pL[g * TQ + t] = p / (red[0] + red[1]);
    // next simT write is safe (readers finished before the barrier above);
    // next red write happens only after the next barrier.
  }
  __syncthreads();

  // ---- phase 3: keys_attn + features (threads 0..255 = one e each) ----
  if (t < 256) {
    const int e = t;
    float ka[G];
    #pragma unroll
    for (int g = 0; g < G; ++g) ka[g] = 0.0f;
    const float* qb = queries + (size_t)b * TQ * E + e;
    const float4* p4 = (const float4*)pL;
    for (int j4 = 0; j4 < TQ / 4; ++j4) {
      float4 pv[G];
      #pragma unroll
      for (int g = 0; g < G; ++g) pv[g] = p4[g * (TQ / 4) + j4];
      #pragma unroll
      for (int c = 0; c < 4; ++c) {
        float qv = qb[(size_t)(j4 * 4 + c) * E];     // coalesced across lanes
        #pragma unroll
        for (int g = 0; g < G; ++g)
          ka[g] += ((const float*)&pv[g])[c] * qv;
      }
    }
    #pragma unroll
    for (int g = 0; g < G; ++g) {
      float kmv = kmask[b * TK + i0 + g];
      float kav = ka[g] * kmv;                        // key-mask scales row
      float kv  = keys[((size_t)b * TK + i0 + g) * E + e];
      featL[g * 2 * E + e]     = kav * kv;            // feature_mul
      float d = kav - kv;
      featL[g * 2 * E + E + e] = d * d;               // feature_sub
    }
  }
  __syncthreads();

  // ---- phase 4: out = relu(feat · Wlast^T + blast), f-split over 2 halves ----
  {
    const int e = t & 255, fh = t >> 8;
    float acc[G];
    #pragma unroll
    for (int g = 0; g < G; ++g) acc[g] = 0.0f;
    const float4* wl4 = (const float4*)(Wlast + (size_t)e * (2 * E)) + fh * 64;
    const float4* f4  = (const float4*)featL + fh * 64;
    #pragma unroll 4
    for (int m = 0; m < 64; ++m) {
      float4 w = wl4[m];                 // thread-private Wlast row (L2-hot)
      #pragma unroll
      for (int g = 0; g < G; ++g) {
        float4 f = f4[g * 128 + m];      // broadcast LDS read
        acc[g] += w.x * f.x + w.y * f.y + w.z * f.z + w.w * f.w;
      }
    }
    float* accL = ct;                    // reuse dead ct LDS
    #pragma unroll
    for (int g = 0; g < G; ++g) accL[fh * (G * 256) + g * 256 + e] = acc[g];
  }
  __syncthreads();
  if (t < 256) {
    const float bl = blast[t];
    const float* accL = ct;
    #pragma unroll
    for (int g = 0; g < G; ++g) {
      float v = accL[g * 256 + t] + accL[G * 256 + g * 256 + t] + bl;
      out[((size_t)b * TK + i0 + g) * E + t] = fmaxf(v, 0.0f);
    }
  }
}

extern "C" void kernel_launch(void* const* d_in, const int* in_sizes, int n_in,
                              void* d_out, int out_size, void* d_ws, size_t ws_size,
                              hipStream_t stream) {
  (void)in_sizes; (void)n_in; (void)out_size; (void)ws_size;
  const float* queries = (const float*)d_in[0];
  const float* keys    = (const float*)d_in[1];
  const float* qmask   = (const float*)d_in[2];
  const float* kmask   = (const float*)d_in[3];
  const float* W1      = (const float*)d_in[4];
  const float* b1      = (const float*)d_in[5];
  const float* W2      = (const float*)d_in[6];
  const float* Wlast   = (const float*)d_in[7];
  const float* blast   = (const float*)d_in[8];
  float* out = (float*)d_out;

  float* A = (float*)d_ws;                      // [B*TK][HP]
  float* C = A + (size_t)B * TK * HP;           // [B*TQ][HP]  (total 1.83 MB)

  prep_ac<<<dim3((B * (TK + TQ)) / 16), dim3(256), 0, stream>>>(
      queries, keys, W1, b1, A, C);
  attn_fused<<<dim3(B * (TK / G)), dim3(512), 0, stream>>>(
      queries, keys, qmask, kmask, W2, Wlast, blast, A, C, out);
}

// Round 2
// 108.964 us; speedup vs baseline: 1.1583x; 1.1583x over previous
//
#include <hip/hip_runtime.h>

// NNSubmulti additive-attention block, MI355X (gfx950).
// B=16, TK=TQ=128, E=256, H=100.
//
// K1 prep_ac:   a[b,i,h] = b1[h] + keys[b,i,:]·W1[h,:E]
//               c[b,j,h] =         queries[b,j,:]·W1[h,E:]   (H padded to 112)
//               + converts Wlast f32 -> bf16 into ws (for K3's MFMA B operand)
// K2 attn_core: per block = batch b x 4 key-rows. sim -> softmax -> p·queries
//               -> feature_mul/feature_sub, written BF16 into d_out (2048x512
//               bf16 == exactly out_size bytes).
// K3 last_gemm: out = relu(feat·Wlast^T + blast) via mfma_f32_16x16x32_bf16.
//               Each block owns 16 feat rows: stages them to LDS, then
//               overwrites the same bytes with the f32 output (race-free:
//               blocks partition rows, N is not split).

namespace {
constexpr int B  = 16;
constexpr int TQ = 128;
constexpr int TK = 128;
constexpr int E  = 256;
constexpr int H  = 100;
constexpr int HP = 112;   // padded H: 4 quarters x 7 float4
constexpr int G  = 4;     // key-rows per attn block -> 512 blocks
}

typedef __attribute__((ext_vector_type(8))) short short8;   // 8 bf16 = 4 VGPRs
typedef __attribute__((ext_vector_type(4))) float f32x4;

__device__ __forceinline__ unsigned short f2bf(float f) {
  unsigned u = __builtin_bit_cast(unsigned, f);
  u = (u + 0x7FFFu + ((u >> 16) & 1u)) >> 16;   // round-to-nearest-even
  return (unsigned short)u;
}

// ---------------------------------------------------------------- K1 ----
__global__ __launch_bounds__(256) void prep_ac(
    const float* __restrict__ queries, const float* __restrict__ keys,
    const float* __restrict__ W1, const float* __restrict__ b1,
    const float* __restrict__ Wlast,
    float* __restrict__ A, float* __restrict__ C,
    unsigned short* __restrict__ Wb /* [256][512] bf16 */) {
  constexpr int RPB = 16;
  __shared__ float xs[RPB * E];          // 16 KB
  const int t  = threadIdx.x;
  const int r0 = blockIdx.x * RPB;       // 256 blocks cover 4096 rows
  const bool isA = (r0 < B * TK);
  const float* src = isA ? (keys + (size_t)r0 * E)
                         : (queries + (size_t)(r0 - B * TK) * E);
  float* dst = isA ? (A + (size_t)r0 * HP)
                   : (C + (size_t)(r0 - B * TK) * HP);

  // Wlast f32 -> bf16 (each block converts 512 elements; 256 blocks cover 131072)
  {
    const int base = blockIdx.x * 512 + t * 2;
    float2 w = *(const float2*)(Wlast + base);
    Wb[base]     = f2bf(w.x);
    Wb[base + 1] = f2bf(w.y);
  }

  {  // stage input rows
    const float4* s4 = (const float4*)src;
    float4* x4 = (float4*)xs;
    #pragma unroll
    for (int m = 0; m < RPB * E / 4 / 256; ++m)
      x4[t + m * 256] = s4[t + m * 256];
  }
  __syncthreads();

  const int h0 = (t & 63) * 2;           // even h in [0,126]
  const int rg = t >> 6;                 // wave id -> rows rg*4..rg*4+3
  if (h0 < H) {                          // h0 even & <100 => h0+1 <= 99 valid
    float acc0[4], acc1[4];
    const float bi0 = isA ? b1[h0] : 0.0f;
    const float bi1 = isA ? b1[h0 + 1] : 0.0f;
    #pragma unroll
    for (int i = 0; i < 4; ++i) { acc0[i] = bi0; acc1[i] = bi1; }
    const float4* w40 = (const float4*)(W1 + (size_t)h0 * (2 * E) + (isA ? 0 : E));
    const float4* w41 = (const float4*)(W1 + (size_t)(h0 + 1) * (2 * E) + (isA ? 0 : E));
    const float4* x4  = (const float4*)xs + (size_t)rg * 4 * (E / 4);
    #pragma unroll 4
    for (int e4 = 0; e4 < E / 4; ++e4) {
      float4 wa = w40[e4], wb = w41[e4];
      #pragma unroll
      for (int i = 0; i < 4; ++i) {
        float4 xv = x4[i * (E / 4) + e4];    // wave-uniform LDS broadcast
        acc0[i] += wa.x * xv.x + wa.y * xv.y + wa.z * xv.z + wa.w * xv.w;
        acc1[i] += wb.x * xv.x + wb.y * xv.y + wb.z * xv.z + wb.w * xv.w;
      }
    }
    #pragma unroll
    for (int i = 0; i < 4; ++i)
      *(float2*)(dst + (size_t)(rg * 4 + i) * HP + h0) = make_float2(acc0[i], acc1[i]);
  } else if (h0 < HP) {                  // pad rows 100..111 -> zero
    #pragma unroll
    for (int i = 0; i < 4; ++i)
      *(float2*)(dst + (size_t)(rg * 4 + i) * HP + h0) = make_float2(0.0f, 0.0f);
  }
}

// ---------------------------------------------------------------- K2 ----
__global__ __launch_bounds__(512) void attn_core(
    const float* __restrict__ queries, const float* __restrict__ keys,
    const float* __restrict__ qmask, const float* __restrict__ kmask,
    const float* __restrict__ W2, const float* __restrict__ A,
    const float* __restrict__ C, unsigned short* __restrict__ feat /* d_out */) {
  __shared__ float a_s[G * HP];
  __shared__ float w2s[HP];
  __shared__ float qm[TQ];
  __shared__ float simP[G * 512];    // 8 KB: per-(g, q, j) partial sims
  __shared__ float pL[G * TQ];       // 2 KB: softmax probabilities
  __shared__ float red[8];

  const int t   = threadIdx.x;
  const int blk = blockIdx.x;        // 512 blocks
  const int b   = blk >> 5;          // 32 blocks per batch
  const int i0  = (blk & 31) * G;

  if (t < G * HP / 4)
    ((float4*)a_s)[t] = ((const float4*)(A + ((size_t)b * TK + i0) * HP))[t];
  if (t < HP) w2s[t] = (t < H) ? W2[t] : 0.0f;
  if (t < TQ) qm[t]  = qmask[b * TQ + t];
  __syncthreads();

  // ---- phase 1: sim partials, no barriers inside ----
  const int j = t & (TQ - 1);
  const int q = t >> 7;              // h-quarter 0..3
  float4 cr[7], wr[7];
  float wsum = 0.0f;
  {
    const float4* c4 = (const float4*)(C + ((size_t)b * TQ + j) * HP + q * 28);
    const float4* w4 = (const float4*)w2s + q * 7;
    #pragma unroll
    for (int k = 0; k < 7; ++k) {
      cr[k] = c4[k];                 // L2-resident, reused across 4 g
      wr[k] = w4[k];
      wsum += wr[k].x + wr[k].y + wr[k].z + wr[k].w;
    }
  }
  {
    const float4* a4p = (const float4*)a_s + q * 7;
    #pragma unroll
    for (int g = 0; g < G; ++g) {
      float s = 0.0f;                // s = sum_h w[h] * rcp(exp(2x)+1)
      #pragma unroll
      for (int k = 0; k < 7; ++k) {
        float4 a4 = a4p[g * (HP / 4) + k];   // wave-uniform broadcast
        float x0 = a4.x + cr[k].x, x1 = a4.y + cr[k].y;
        float x2 = a4.z + cr[k].z, x3 = a4.w + cr[k].w;
        s = fmaf(wr[k].x, __builtin_amdgcn_rcpf(__expf(x0 + x0) + 1.0f), s);
        s = fmaf(wr[k].y, __builtin_amdgcn_rcpf(__expf(x1 + x1) + 1.0f), s);
        s = fmaf(wr[k].z, __builtin_amdgcn_rcpf(__expf(x2 + x2) + 1.0f), s);
        s = fmaf(wr[k].w, __builtin_amdgcn_rcpf(__expf(x3 + x3) + 1.0f), s);
      }
      simP[g * 512 + t] = wsum - 2.0f * s;   // sum_h w*(1-2r) for this quarter
    }
  }
  __syncthreads();

  // ---- phase 2: softmax for all G rows in parallel ----
  {
    const int g2 = t >> 7, j2 = t & 127;
    const float* sp = simP + g2 * 512 + j2;
    float sv = sp[0] + sp[128] + sp[256] + sp[384];
    if (qm[j2] == 0.0f) sv = -4294967295.0f;   // -2^32+1
    float p = __expf(sv);                       // |sim| <= sum|W2| ~ 24: safe
    float s = p;
    #pragma unroll
    for (int off = 1; off < 64; off <<= 1) s += __shfl_xor(s, off, 64);
    if ((t & 63) == 0) red[t >> 6] = s;
    __syncthreads();
    pL[t] = p / (red[g2 * 2] + red[g2 * 2 + 1]);
  }
  __syncthreads();

  // ---- phase 3: keys_attn + features, all 512 threads (2 g each) ----
  {
    const int e = t & 255, gh = t >> 8;
    float ka0 = 0.0f, ka1 = 0.0f;
    const float* qb = queries + (size_t)b * TQ * E + e;
    const float4* p4 = (const float4*)pL;
    for (int j4 = 0; j4 < TQ / 4; ++j4) {
      float4 p0 = p4[(gh * 2) * 32 + j4];      // broadcast
      float4 p1 = p4[(gh * 2 + 1) * 32 + j4];
      #pragma unroll
      for (int c = 0; c < 4; ++c) {
        float qv = qb[(size_t)(j4 * 4 + c) * E];   // coalesced
        ka0 = fmaf(((const float*)&p0)[c], qv, ka0);
        ka1 = fmaf(((const float*)&p1)[c], qv, ka1);
      }
    }
    #pragma unroll
    for (int gg = 0; gg < 2; ++gg) {
      const int g = gh * 2 + gg;
      const float ka = gg ? ka1 : ka0;
      const float kmv = kmask[b * TK + i0 + g];
      const float kav = ka * kmv;
      const float kv  = keys[((size_t)b * TK + i0 + g) * E + e];
      const size_t row = (size_t)(b * TK + i0 + g) * (2 * E);
      feat[row + e]     = f2bf(kav * kv);          // feature_mul
      float d = kav - kv;
      feat[row + E + e] = f2bf(d * d);             // feature_sub
    }
  }
}

// ---------------------------------------------------------------- K3 ----
// out[m, e] = relu( sum_f feat[m, f] * Wlast[e, f] + blast[e] )
// M=2048 rows, N=256, K=512. Block = 16 rows x all 256 cols -> 128 blocks.
// feat (bf16) lives in d_out; staged to LDS before being overwritten.
__global__ __launch_bounds__(256) void last_gemm(
    const unsigned short* __restrict__ Wb /* [256][512] bf16 */,
    const float* __restrict__ blast, float* __restrict__ out) {
  __shared__ short A_s[16 * 520];    // 16 rows x (512 + 8 pad) bf16 = 16.6 KB
  __shared__ short B_s[256 * 72];    // 256 n-rows x (64 + 8 pad) bf16 = 36 KB
  const int t  = threadIdx.x;
  const int m0 = blockIdx.x * 16;

  // stage all 16 feat rows (full K) from d_out
  {
    const uint4* src = (const uint4*)out;     // feat row = 512 bf16 = 64 uint4
    #pragma unroll
    for (int i = 0; i < 4; ++i) {
      int idx = t + i * 256;
      int r = idx >> 6, c = idx & 63;
      *(uint4*)(A_s + r * 520 + c * 8) = src[(size_t)(m0 + r) * 64 + c];
    }
  }
  __syncthreads();

  f32x4 acc[4];
  #pragma unroll
  for (int nt = 0; nt < 4; ++nt) acc[nt] = f32x4{0.f, 0.f, 0.f, 0.f};

  const int wave = t >> 6, lane = t & 63;
  const int nsub = wave * 64;                 // 4 waves x 64 N-cols
  const int m    = lane & 15, kq = lane >> 4;

  for (int kc = 0; kc < 8; ++kc) {            // K chunks of 64
    // stage B chunk (bf16 source): 256 rows x 64 bf16
    #pragma unroll
    for (int i = 0; i < 8; ++i) {
      int idx = t + i * 256;
      int r = idx >> 3, p = idx & 7;          // 8x16B per row
      *(uint4*)(B_s + r * 72 + p * 8) =
          ((const uint4*)(Wb + (size_t)r * 512 + kc * 64))[p];
    }
    __syncthreads();
    #pragma unroll
    for (int ks = 0; ks < 2; ++ks) {
      short8 a = *(const short8*)(A_s + m * 520 + kc * 64 + ks * 32 + kq * 8);
      #pragma unroll
      for (int nt = 0; nt < 4; ++nt) {
        short8 bf = *(const short8*)(B_s + (nsub + nt * 16 + m) * 72 + ks * 32 + kq * 8);
        acc[nt] = __builtin_amdgcn_mfma_f32_16x16x32_bf16(a, bf, acc[nt], 0, 0, 0);
      }
    }
    __syncthreads();
  }

  // epilogue: D row = (lane>>4)*4 + reg (M), col = lane&15 (N)
  const int col = lane & 15;
  const int rbase = m0 + (lane >> 4) * 4;
  #pragma unroll
  for (int nt = 0; nt < 4; ++nt) {
    const int e = nsub + nt * 16 + col;
    const float bl = blast[e];
    #pragma unroll
    for (int r = 0; r < 4; ++r)
      out[(size_t)(rbase + r) * 256 + e] = fmaxf(acc[nt][r] + bl, 0.0f);
  }
}

// ------------------------------------------------------------- launch ----
extern "C" void kernel_launch(void* const* d_in, const int* in_sizes, int n_in,
                              void* d_out, int out_size, void* d_ws, size_t ws_size,
                              hipStream_t stream) {
  (void)in_sizes; (void)n_in; (void)out_size; (void)ws_size;
  const float* queries = (const float*)d_in[0];
  const float* keys    = (const float*)d_in[1];
  const float* qmask   = (const float*)d_in[2];
  const float* kmask   = (const float*)d_in[3];
  const float* W1      = (const float*)d_in[4];
  const float* b1      = (const float*)d_in[5];
  const float* W2      = (const float*)d_in[6];
  const float* Wlast   = (const float*)d_in[7];
  const float* blast   = (const float*)d_in[8];
  float* out = (float*)d_out;

  float* A = (float*)d_ws;                               // [2048][112] f32
  float* C = A + (size_t)B * TK * HP;                    // [2048][112] f32
  unsigned short* Wb = (unsigned short*)(C + (size_t)B * TQ * HP);  // [256][512] bf16
  // total ws: 917504 + 917504 + 262144 = 2 MiB

  prep_ac<<<dim3(256), dim3(256), 0, stream>>>(queries, keys, W1, b1, Wlast, A, C, Wb);
  attn_core<<<dim3(B * (TK / G)), dim3(512), 0, stream>>>(
      queries, keys, qmask, kmask, W2, A, C, (unsigned short*)out);
  last_gemm<<<dim3(B * TK / 16), dim3(256), 0, stream>>>(Wb, blast, out);
}

// Round 3
// 99.082 us; speedup vs baseline: 1.2738x; 1.0997x over previous
//
#include <hip/hip_runtime.h>

// NNSubmulti additive-attention block, MI355X (gfx950).
// B=16, TK=TQ=128, E=256, H=100.
//
// K0 convert_bf16: keys||queries -> Xb bf16 [4096][256]; W1 -> Wb1 bf16
//                  [112][512] (zero-pad h>=100); Wlast -> Wb bf16 [256][512].
// K1 prep_mfma:    a[b,i,h] = b1[h] + keys[b,i,:]·W1[h,:E]
//                  c[b,j,h] =         queries[b,j,:]·W1[h,E:]
//                  as bf16 MFMA GEMM, f32 out to ws (HP=112 padded, pads = 0).
// K2 attn_core:    per block = batch b x 4 key-rows. sim -> softmax ->
//                  p·queries -> features, written BF16 into d_out.
// K3 last_gemm:    out = relu(feat·Wlast^T + blast) via mfma (bf16).

namespace {
constexpr int B  = 16;
constexpr int TQ = 128;
constexpr int TK = 128;
constexpr int E  = 256;
constexpr int H  = 100;
constexpr int HP = 112;   // padded H: 4 quarters x 7 float4
constexpr int G  = 4;     // key-rows per attn block -> 512 blocks
}

typedef __attribute__((ext_vector_type(8))) short short8;   // 8 bf16 = 4 VGPRs
typedef __attribute__((ext_vector_type(4))) float f32x4;

__device__ __forceinline__ unsigned short f2bf(float f) {
  unsigned u = __builtin_bit_cast(unsigned, f);
  u = (u + 0x7FFFu + ((u >> 16) & 1u)) >> 16;   // round-to-nearest-even
  return (unsigned short)u;
}

// ---------------------------------------------------------------- K0 ----
__global__ __launch_bounds__(256) void convert_bf16(
    const float* __restrict__ queries, const float* __restrict__ keys,
    const float* __restrict__ W1, const float* __restrict__ Wlast,
    unsigned short* __restrict__ Xb, unsigned short* __restrict__ Wb1,
    unsigned short* __restrict__ Wb) {
  const int blk = blockIdx.x, t = threadIdx.x;
  if (blk < 1024) {                       // Xb: 4096x256
    const int idx = blk * 1024 + t * 4;
    const int row = idx >> 8, e = idx & 255;
    const float* src = (row < B * TK) ? keys + (size_t)row * E + e
                                      : queries + (size_t)(row - B * TK) * E + e;
    float4 v = *(const float4*)src;
    ushort4 o = make_ushort4(f2bf(v.x), f2bf(v.y), f2bf(v.z), f2bf(v.w));
    *(ushort4*)(Xb + idx) = o;
  } else if (blk < 1080) {                // Wb1: 112x512, zero-pad h>=100
    const int idx = (blk - 1024) * 1024 + t * 4;
    const int h = idx >> 9;
    float4 v = (h < H) ? *(const float4*)(W1 + idx)
                       : make_float4(0.f, 0.f, 0.f, 0.f);
    ushort4 o = make_ushort4(f2bf(v.x), f2bf(v.y), f2bf(v.z), f2bf(v.w));
    *(ushort4*)(Wb1 + idx) = o;
  } else {                                // Wb: 256x512
    const int idx = (blk - 1080) * 1024 + t * 4;
    float4 v = *(const float4*)(Wlast + idx);
    ushort4 o = make_ushort4(f2bf(v.x), f2bf(v.y), f2bf(v.z), f2bf(v.w));
    *(ushort4*)(Wb + idx) = o;
  }
}

// ---------------------------------------------------------------- K1 ----
// Block = 16 X-rows x 112 h. A = Xb rows (bf16, [M][K]); B = Wb1 half
// ([N=h][K=e], native layout). 7 N-tiles of 16, K = 256 (8 mfma steps).
__global__ __launch_bounds__(256) void prep_mfma(
    const unsigned short* __restrict__ Xb, const unsigned short* __restrict__ Wb1,
    const float* __restrict__ b1, float* __restrict__ A, float* __restrict__ C) {
  __shared__ short Bs[112 * 264];   // 59.1 KB (row stride 264 shorts: +8 pad)
  __shared__ short As[16 * 264];    //  8.4 KB
  const int t  = threadIdx.x;
  const int m0 = blockIdx.x * 16;          // 256 blocks cover 4096 rows
  const bool isA = (m0 < B * TK);
  const int koff = isA ? 0 : 256;          // W1[:, :E] vs W1[:, E:]
  float* dst = isA ? (A + (size_t)m0 * HP)
                   : (C + (size_t)(m0 - B * TK) * HP);

  #pragma unroll
  for (int i = 0; i < 14; ++i) {           // stage B: 112 x 256 bf16, coalesced
    const int idx = i * 256 + t;
    const int h = idx >> 5, seg = idx & 31;
    *(uint4*)(Bs + h * 264 + seg * 8) =
        *(const uint4*)(Wb1 + (size_t)h * 512 + koff + seg * 8);
  }
  #pragma unroll
  for (int i = 0; i < 2; ++i) {            // stage A: 16 x 256 bf16
    const int idx = i * 256 + t;
    const int r = idx >> 5, seg = idx & 31;
    *(uint4*)(As + r * 264 + seg * 8) =
        *(const uint4*)(Xb + (size_t)(m0 + r) * 256 + seg * 8);
  }
  __syncthreads();

  const int wave = t >> 6, lane = t & 63;
  const int m = lane & 15, kq = lane >> 4;
  const int nt0 = wave, nt1 = wave + 4;    // tiles {w, w+4}; wave3 has 1 tile
  f32x4 acc0 = {0.f, 0.f, 0.f, 0.f}, acc1 = {0.f, 0.f, 0.f, 0.f};

  #pragma unroll
  for (int kc = 0; kc < 8; ++kc) {
    short8 a = *(const short8*)(As + m * 264 + kc * 32 + kq * 8);
    short8 bv0 = *(const short8*)(Bs + (nt0 * 16 + m) * 264 + kc * 32 + kq * 8);
    acc0 = __builtin_amdgcn_mfma_f32_16x16x32_bf16(a, bv0, acc0, 0, 0, 0);
    if (nt1 < 7) {
      short8 bv1 = *(const short8*)(Bs + (nt1 * 16 + m) * 264 + kc * 32 + kq * 8);
      acc1 = __builtin_amdgcn_mfma_f32_16x16x32_bf16(a, bv1, acc1, 0, 0, 0);
    }
  }

  // epilogue: D col=lane&15 -> h (N), row=(lane>>4)*4+reg -> X-row (M)
  const int rbase = (lane >> 4) * 4;
  {
    const int h = nt0 * 16 + m;
    const float bias = (isA && h < H) ? b1[h] : 0.0f;
    #pragma unroll
    for (int r = 0; r < 4; ++r)
      dst[(size_t)(rbase + r) * HP + h] = acc0[r] + bias;
  }
  if (nt1 < 7) {
    const int h = nt1 * 16 + m;
    const float bias = (isA && h < H) ? b1[h] : 0.0f;
    #pragma unroll
    for (int r = 0; r < 4; ++r)
      dst[(size_t)(rbase + r) * HP + h] = acc1[r] + bias;
  }
}

// ---------------------------------------------------------------- K2 ----
__global__ __launch_bounds__(512) void attn_core(
    const float* __restrict__ queries, const float* __restrict__ keys,
    const float* __restrict__ qmask, const float* __restrict__ kmask,
    const float* __restrict__ W2, const float* __restrict__ A,
    const float* __restrict__ C, unsigned short* __restrict__ feat /* d_out */) {
  __shared__ float a_s[G * HP];
  __shared__ float w2s[HP];
  __shared__ float qm[TQ];
  __shared__ float simP[G * 512];    // 8 KB: per-(g, q, j) partial sims
  __shared__ float pL[G * TQ];       // 2 KB: softmax probabilities
  __shared__ float red[8];

  const int t   = threadIdx.x;
  const int blk = blockIdx.x;        // 512 blocks
  const int b   = blk >> 5;          // 32 blocks per batch
  const int i0  = (blk & 31) * G;

  if (t < G * HP / 4)
    ((float4*)a_s)[t] = ((const float4*)(A + ((size_t)b * TK + i0) * HP))[t];
  if (t < HP) w2s[t] = (t < H) ? W2[t] : 0.0f;
  if (t < TQ) qm[t]  = qmask[b * TQ + t];
  __syncthreads();

  // ---- phase 1: sim partials, no barriers inside ----
  const int j = t & (TQ - 1);
  const int q = t >> 7;              // h-quarter 0..3
  float4 cr[7], wr[7];
  float wsum = 0.0f;
  {
    const float4* c4 = (const float4*)(C + ((size_t)b * TQ + j) * HP + q * 28);
    const float4* w4 = (const float4*)w2s + q * 7;
    #pragma unroll
    for (int k = 0; k < 7; ++k) {
      cr[k] = c4[k];                 // L2-resident, reused across 4 g
      wr[k] = w4[k];
      wsum += wr[k].x + wr[k].y + wr[k].z + wr[k].w;
    }
  }
  {
    const float4* a4p = (const float4*)a_s + q * 7;
    #pragma unroll
    for (int g = 0; g < G; ++g) {
      float s = 0.0f;                // s = sum_h w[h] * rcp(exp(2x)+1)
      #pragma unroll
      for (int k = 0; k < 7; ++k) {
        float4 a4 = a4p[g * (HP / 4) + k];   // wave-uniform broadcast
        float x0 = a4.x + cr[k].x, x1 = a4.y + cr[k].y;
        float x2 = a4.z + cr[k].z, x3 = a4.w + cr[k].w;
        s = fmaf(wr[k].x, __builtin_amdgcn_rcpf(__expf(x0 + x0) + 1.0f), s);
        s = fmaf(wr[k].y, __builtin_amdgcn_rcpf(__expf(x1 + x1) + 1.0f), s);
        s = fmaf(wr[k].z, __builtin_amdgcn_rcpf(__expf(x2 + x2) + 1.0f), s);
        s = fmaf(wr[k].w, __builtin_amdgcn_rcpf(__expf(x3 + x3) + 1.0f), s);
      }
      simP[g * 512 + t] = wsum - 2.0f * s;   // sum_h w*(1-2r) for this quarter
    }
  }
  __syncthreads();

  // ---- phase 2: softmax for all G rows in parallel ----
  {
    const int g2 = t >> 7, j2 = t & 127;
    const float* sp = simP + g2 * 512 + j2;
    float sv = sp[0] + sp[128] + sp[256] + sp[384];
    if (qm[j2] == 0.0f) sv = -4294967295.0f;   // -2^32+1
    float p = __expf(sv);                       // |sim| <= sum|W2| ~ 24: safe
    float s = p;
    #pragma unroll
    for (int off = 1; off < 64; off <<= 1) s += __shfl_xor(s, off, 64);
    if ((t & 63) == 0) red[t >> 6] = s;
    __syncthreads();
    pL[t] = p / (red[g2 * 2] + red[g2 * 2 + 1]);
  }
  __syncthreads();

  // ---- phase 3: keys_attn + features, all 512 threads (2 g each) ----
  {
    const int e = t & 255, gh = t >> 8;
    float ka0 = 0.0f, ka1 = 0.0f;
    const float* qb = queries + (size_t)b * TQ * E + e;
    const float4* p4 = (const float4*)pL;
    for (int j4 = 0; j4 < TQ / 4; ++j4) {
      float4 p0 = p4[(gh * 2) * 32 + j4];      // broadcast
      float4 p1 = p4[(gh * 2 + 1) * 32 + j4];
      #pragma unroll
      for (int c = 0; c < 4; ++c) {
        float qv = qb[(size_t)(j4 * 4 + c) * E];   // coalesced
        ka0 = fmaf(((const float*)&p0)[c], qv, ka0);
        ka1 = fmaf(((const float*)&p1)[c], qv, ka1);
      }
    }
    #pragma unroll
    for (int gg = 0; gg < 2; ++gg) {
      const int g = gh * 2 + gg;
      const float ka = gg ? ka1 : ka0;
      const float kmv = kmask[b * TK + i0 + g];
      const float kav = ka * kmv;
      const float kv  = keys[((size_t)b * TK + i0 + g) * E + e];
      const size_t row = (size_t)(b * TK + i0 + g) * (2 * E);
      feat[row + e]     = f2bf(kav * kv);          // feature_mul
      float d = kav - kv;
      feat[row + E + e] = f2bf(d * d);             // feature_sub
    }
  }
}

// ---------------------------------------------------------------- K3 ----
// out[m, e] = relu( sum_f feat[m, f] * Wlast[e, f] + blast[e] )
// M=2048 rows, N=256, K=512. Block = 16 rows x all 256 cols -> 128 blocks.
// feat (bf16) lives in d_out; staged to LDS before being overwritten.
__global__ __launch_bounds__(256) void last_gemm(
    const unsigned short* __restrict__ Wb /* [256][512] bf16 */,
    const float* __restrict__ blast, float* __restrict__ out) {
  __shared__ short A_s[16 * 520];    // 16 rows x (512 + 8 pad) bf16 = 16.6 KB
  __shared__ short B_s[256 * 72];    // 256 n-rows x (64 + 8 pad) bf16 = 36 KB
  const int t  = threadIdx.x;
  const int m0 = blockIdx.x * 16;

  // stage all 16 feat rows (full K) from d_out
  {
    const uint4* src = (const uint4*)out;     // feat row = 512 bf16 = 64 uint4
    #pragma unroll
    for (int i = 0; i < 4; ++i) {
      int idx = t + i * 256;
      int r = idx >> 6, c = idx & 63;
      *(uint4*)(A_s + r * 520 + c * 8) = src[(size_t)(m0 + r) * 64 + c];
    }
  }
  __syncthreads();

  f32x4 acc[4];
  #pragma unroll
  for (int nt = 0; nt < 4; ++nt) acc[nt] = f32x4{0.f, 0.f, 0.f, 0.f};

  const int wave = t >> 6, lane = t & 63;
  const int nsub = wave * 64;                 // 4 waves x 64 N-cols
  const int m    = lane & 15, kq = lane >> 4;

  for (int kc = 0; kc < 8; ++kc) {            // K chunks of 64
    // stage B chunk (bf16 source): 256 rows x 64 bf16
    #pragma unroll
    for (int i = 0; i < 8; ++i) {
      int idx = t + i * 256;
      int r = idx >> 3, p = idx & 7;          // 8x16B per row
      *(uint4*)(B_s + r * 72 + p * 8) =
          ((const uint4*)(Wb + (size_t)r * 512 + kc * 64))[p];
    }
    __syncthreads();
    #pragma unroll
    for (int ks = 0; ks < 2; ++ks) {
      short8 a = *(const short8*)(A_s + m * 520 + kc * 64 + ks * 32 + kq * 8);
      #pragma unroll
      for (int nt = 0; nt < 4; ++nt) {
        short8 bf = *(const short8*)(B_s + (nsub + nt * 16 + m) * 72 + ks * 32 + kq * 8);
        acc[nt] = __builtin_amdgcn_mfma_f32_16x16x32_bf16(a, bf, acc[nt], 0, 0, 0);
      }
    }
    __syncthreads();
  }

  // epilogue: D row = (lane>>4)*4 + reg (M), col = lane&15 (N)
  const int col = lane & 15;
  const int rbase = m0 + (lane >> 4) * 4;
  #pragma unroll
  for (int nt = 0; nt < 4; ++nt) {
    const int e = nsub + nt * 16 + col;
    const float bl = blast[e];
    #pragma unroll
    for (int r = 0; r < 4; ++r)
      out[(size_t)(rbase + r) * 256 + e] = fmaxf(acc[nt][r] + bl, 0.0f);
  }
}

// ------------------------------------------------------------- launch ----
extern "C" void kernel_launch(void* const* d_in, const int* in_sizes, int n_in,
                              void* d_out, int out_size, void* d_ws, size_t ws_size,
                              hipStream_t stream) {
  (void)in_sizes; (void)n_in; (void)out_size; (void)ws_size;
  const float* queries = (const float*)d_in[0];
  const float* keys    = (const float*)d_in[1];
  const float* qmask   = (const float*)d_in[2];
  const float* kmask   = (const float*)d_in[3];
  const float* W1      = (const float*)d_in[4];
  const float* b1      = (const float*)d_in[5];
  const float* W2      = (const float*)d_in[6];
  const float* Wlast   = (const float*)d_in[7];
  const float* blast   = (const float*)d_in[8];
  float* out = (float*)d_out;

  float* A = (float*)d_ws;                               // [2048][112] f32
  float* C = A + (size_t)B * TK * HP;                    // [2048][112] f32
  unsigned short* Wb  = (unsigned short*)(C + (size_t)B * TQ * HP); // [256][512]
  unsigned short* Wb1 = Wb + (size_t)256 * 512;          // [112][512] bf16
  unsigned short* Xb  = Wb1 + (size_t)112 * 512;         // [4096][256] bf16
  // total ws ~ 4.1 MiB

  convert_bf16<<<dim3(1208), dim3(256), 0, stream>>>(
      queries, keys, W1, Wlast, Xb, Wb1, Wb);
  prep_mfma<<<dim3(256), dim3(256), 0, stream>>>(Xb, Wb1, b1, A, C);
  attn_core<<<dim3(B * (TK / G)), dim3(512), 0, stream>>>(
      queries, keys, qmask, kmask, W2, A, C, (unsigned short*)out);
  last_gemm<<<dim3(B * TK / 16), dim3(256), 0, stream>>>(Wb, blast, out);
}